// Round 10
// baseline (1055.863 us; speedup 1.0000x reference)
//
#include <hip/hip_runtime.h>
#include <math.h>

#define IMG 512
#define NB 32
#define NA 180
#define NA2 90                   // angles actually gathered (90-deg symmetry)
#define PW2 513                  // padded cols: x in [-1, 511]
#define PH2 513                  // padded rows: y in [-1, 511]
#define NR2 (PW2 * PH2)          // 263169 records, 128 B each
#define NCH 8                    // 64-line chunks per angle

typedef int v4i __attribute__((ext_vector_type(4)));

// CK-style raw buffer load intrinsic mapping (32-bit voffset addressing).
__device__ v4i llvm_amdgcn_raw_buffer_load_v4i32(
    v4i srsrc, int voffset, int soffset, int aux) __asm("llvm.amdgcn.raw.buffer.load.v4i32");

// ---------------------------------------------------------------------------
// u8 dot4: acc += sum of byte-wise products (bytes <= 127: signed==unsigned).
// ---------------------------------------------------------------------------
__device__ __forceinline__ int dot4u(unsigned a, unsigned b, int c) {
#if __has_builtin(__builtin_amdgcn_udot4)
    return (int)__builtin_amdgcn_udot4(a, b, (unsigned)c, false);
#elif __has_builtin(__builtin_amdgcn_sdot4)
    return __builtin_amdgcn_sdot4((int)a, (int)b, c, false);
#else
    int s = c;
    s += (int)((a      ) & 0xffu) * (int)((b      ) & 0xffu);
    s += (int)((a >>  8) & 0xffu) * (int)((b >>  8) & 0xffu);
    s += (int)((a >> 16) & 0xffu) * (int)((b >> 16) & 0xffu);
    s += (int)((a >> 24)        ) * (int)((b >> 24)        );
    return s;
#endif
}

// ---------------------------------------------------------------------------
// Stage 1: quantize + transpose. x[n][y][x] fp32 -> xu8[y*512+x][n] u8.
// ---------------------------------------------------------------------------
__global__ __launch_bounds__(256) void quantize8(
    const float* __restrict__ x, unsigned char* __restrict__ xu8) {
    __shared__ float lds[64 * 33];
    const int p0  = blockIdx.x * 64;
    const int t   = threadIdx.x;
    const int pix = t & 63;
    const int nb  = t >> 6;  // 0..3

    #pragma unroll
    for (int k = 0; k < 8; ++k) {
        const int n = nb + 4 * k;
        lds[pix * 33 + n] = x[(size_t)n * (IMG * IMG) + p0 + pix];
    }
    __syncthreads();

    const int pp = t >> 2;
    const int n0 = (t & 3) * 8;
    unsigned w0 = 0, w1 = 0;
    #pragma unroll
    for (int m = 0; m < 4; ++m) {
        const unsigned b = (unsigned)fmaf(lds[pp * 33 + n0 + m], 127.0f, 0.5f);
        w0 |= b << (8 * m);
    }
    #pragma unroll
    for (int m = 0; m < 4; ++m) {
        const unsigned b = (unsigned)fmaf(lds[pp * 33 + n0 + 4 + m], 127.0f, 0.5f);
        w1 |= b << (8 * m);
    }
    uint2 st = make_uint2(w0, w1);
    *reinterpret_cast<uint2*>(xu8 + (size_t)(p0 + pp) * 32 + (t & 3) * 8) = st;
}

// ---------------------------------------------------------------------------
// Stage 2: build zero-padded u8 quad table from the u8 image.
// ---------------------------------------------------------------------------
__global__ __launch_bounds__(256) void build_quads8(
    const unsigned char* __restrict__ xu8, uint4* __restrict__ xq) {
    const int t = threadIdx.x;
    const int q = t & 3;
    const int r = blockIdx.x * 64 + (t >> 2);
    if (r >= NR2) return;
    const int row = r / PW2;
    const int col = r - row * PW2;
    const int y  = row - 1;
    const int xx = col - 1;

    const bool y0ok = (unsigned)y        < 512u;
    const bool y1ok = (unsigned)(y + 1)  < 512u;
    const bool x0ok = (unsigned)xx       < 512u;
    const bool x1ok = (unsigned)(xx + 1) < 512u;
    const int off = q * 8;

    const uint2 z = make_uint2(0u, 0u);
    uint2 a00 = z, a01 = z, a10 = z, a11 = z;
    if (y0ok && x0ok) a00 = *reinterpret_cast<const uint2*>(xu8 + (size_t)(y * IMG + xx) * 32 + off);
    if (y0ok && x1ok) a01 = *reinterpret_cast<const uint2*>(xu8 + (size_t)(y * IMG + xx + 1) * 32 + off);
    if (y1ok && x0ok) a10 = *reinterpret_cast<const uint2*>(xu8 + (size_t)((y + 1) * IMG + xx) * 32 + off);
    if (y1ok && x1ok) a11 = *reinterpret_cast<const uint2*>(xu8 + (size_t)((y + 1) * IMG + xx + 1) * 32 + off);

    unsigned w[8];
    #pragma unroll
    for (int m = 0; m < 4; ++m) {
        w[m] = ((a00.x >> (8 * m)) & 0xffu)
             | (((a01.x >> (8 * m)) & 0xffu) << 8)
             | (((a10.x >> (8 * m)) & 0xffu) << 16)
             | (((a11.x >> (8 * m)) & 0xffu) << 24);
        w[4 + m] = ((a00.y >> (8 * m)) & 0xffu)
                 | (((a01.y >> (8 * m)) & 0xffu) << 8)
                 | (((a10.y >> (8 * m)) & 0xffu) << 16)
                 | (((a11.y >> (8 * m)) & 0xffu) << 24);
    }
    xq[(size_t)r * 8 + q * 2]     = make_uint4(w[0], w[1], w[2], w[3]);
    xq[(size_t)r * 8 + q * 2 + 1] = make_uint4(w[4], w[5], w[6], w[7]);
}

// ---------------------------------------------------------------------------
// Legacy one-pass build (fallback path only).
// ---------------------------------------------------------------------------
__global__ __launch_bounds__(256) void build_quads(
    const float* __restrict__ x, uint4* __restrict__ xq) {
    const int t = threadIdx.x;
    const int q = t & 3;
    const int r = blockIdx.x * 64 + (t >> 2);
    if (r >= NR2) return;
    const int row = r / PW2;
    const int col = r - row * PW2;
    const int y  = row - 1;
    const int xx = col - 1;

    const bool y0ok = (unsigned)y        < 512u;
    const bool y1ok = (unsigned)(y + 1)  < 512u;
    const bool x0ok = (unsigned)xx       < 512u;
    const bool x1ok = (unsigned)(xx + 1) < 512u;
    const int ys0 = y0ok ? y : 0,  ys1 = y1ok ? y + 1 : 0;
    const int xs0 = x0ok ? xx : 0, xs1 = x1ok ? xx + 1 : 0;

    const float* base = x + (size_t)(q * 8) * (IMG * IMG);
    unsigned wv[8];
    #pragma unroll
    for (int m = 0; m < 8; ++m) {
        const float* p = base + (size_t)m * (IMG * IMG);
        const float v00 = (y0ok && x0ok) ? p[ys0 * IMG + xs0] : 0.0f;
        const float v01 = (y0ok && x1ok) ? p[ys0 * IMG + xs1] : 0.0f;
        const float v10 = (y1ok && x0ok) ? p[ys1 * IMG + xs0] : 0.0f;
        const float v11 = (y1ok && x1ok) ? p[ys1 * IMG + xs1] : 0.0f;
        const unsigned q00 = (unsigned)fmaf(v00, 127.0f, 0.5f);
        const unsigned q01 = (unsigned)fmaf(v01, 127.0f, 0.5f);
        const unsigned q10 = (unsigned)fmaf(v10, 127.0f, 0.5f);
        const unsigned q11 = (unsigned)fmaf(v11, 127.0f, 0.5f);
        wv[m] = q00 | (q01 << 8) | (q10 << 16) | (q11 << 24);
    }
    xq[(size_t)r * 8 + q * 2]     = make_uint4(wv[0], wv[1], wv[2], wv[3]);
    xq[(size_t)r * 8 + q * 2 + 1] = make_uint4(wv[4], wv[5], wv[6], wv[7]);
}

// ---------------------------------------------------------------------------
// Symmetric radon v9: round-7's 4-wave structure at the SAFE launch bounds.
// LAUNCH-BOUNDS (empirical, rounds 5-9): 2nd arg = min BLOCKS/CU.
//   (512,2) -> 16 waves/CU -> 128-VGPR cap -> no spill (rounds 6,9: 92-104).
//   (512,4) -> 32 waves/CU -> 64 cap -> spill (round 8). (256,5) -> VGPR 48
//   spill (round 7). (256,4) = 16 waves/CU -> 128 cap = the (512,2) analog.
// Rounds 6/9 diagnosis: VALU 53%, all pipes ~50%, occupancy ~20% -- the
// 8-wave/2-block/CU shape is concurrency-limited with a 33% tail
// (720 blocks = 2.8/CU). This kernel: block = (angle, 64-line chunk jc,
// i-half ih), 4 waves, grid 1440 = 5.6/CU, 4-5 resident blocks/CU ->
// tail ~12% + more independent streams. Single-deep pipeline (2-deep was
// neutral, round 9). Wave w owns i-segment 256*ih + [64w, 64w+64).
// Rows: shfl reduce + LDS atomics -> int rowpart[ih] slab (merged in
// transpose). Columns: register colv[8][4] -> colpart[a][jc] slab,
// i-halves disjoint. Zero global atomics, zero memset.
// ---------------------------------------------------------------------------
__global__ __launch_bounds__(256, 4) void radon_sym9(
    const uint4* __restrict__ xq, int* __restrict__ rowpart,
    int* __restrict__ colpart) {
    const int gid = blockIdx.x;       // 90*8*2 = 1440
    const int a   = gid >> 4;         // 0..89
    const int rem = gid & 15;
    const int jc  = rem >> 1;         // 0..7 : 64-line chunk
    const int ih  = rem & 1;          // i-half
    const int j0  = jc << 6;

    const int t = threadIdx.x;
    const int w = t >> 6;             // wave 0..3
    const int l = t & 63;
    const int g = l >> 3;             // sample group (8 samples)
    const int q = l & 7;              // record slice: batches 4q..4q+3
    const int qoff = q << 4;

    __shared__ uint2 cobuf[4][2][144];   // [wave][slot][18g+q], conflict-free b128
    __shared__ int   row_lds[64 * 33];

    for (int e = t; e < 64 * 33; e += 256) row_lds[e] = 0;

    union { v4i v; struct { unsigned lo, hi, sz, cfg; } s; } srd;
    srd.s.lo  = (unsigned)(size_t)xq;
    srd.s.hi  = (unsigned)((size_t)xq >> 32);
    srd.s.sz  = (unsigned)NR2 * 128u;
    srd.s.cfg = 0x00020000u;

    const float theta = (float)a * (float)(M_PI / 180.0);
    float s, c;
    sincosf(theta, &s, &c);
    const float fi = (float)(256 * ih + 64 * w + l);   // this lane's sample i

    int colv[8][4];
    #pragma unroll
    for (int p = 0; p < 8; ++p)
        #pragma unroll
        for (int m = 0; m < 4; ++m) colv[p][m] = 0;

    auto COORD = [&](int jl, int slot) {
        const int j = j0 + jl;
        const float cj = ((float)j + 0.5f) * (2.0f / 512.0f) - 1.0f;
        const float P = 256.0f * c * cj + s * (0.5f - 256.0f) + 255.5f;
        const float Q = -256.0f * s * cj + c * (0.5f - 256.0f) + 255.5f;
        const float ix = fminf(fmaxf(fmaf(fi, s, P), -1.0f), 511.9995f);
        const float iy = fminf(fmaxf(fmaf(fi, c, Q), -1.0f), 511.9995f);
        const float ix0f = floorf(ix), iy0f = floorf(iy);
        const float wx1 = ix - ix0f, wy1 = iy - iy0f;
        const float wx0 = 1.0f - wx1, wy0 = 1.0f - wy1;
        const unsigned q00 = (unsigned)fmaf(wy0 * wx0, 127.0f, 0.5f);
        const unsigned q01 = (unsigned)fmaf(wy0 * wx1, 127.0f, 0.5f);
        const unsigned q10 = (unsigned)fmaf(wy1 * wx0, 127.0f, 0.5f);
        const unsigned q11 = (unsigned)fmaf(wy1 * wx1, 127.0f, 0.5f);
        cobuf[w][slot][18 * g + q] =
            make_uint2((unsigned)(((int)iy0f + 1) * PW2 + ((int)ix0f + 1)),
                       q00 | (q01 << 8) | (q10 << 16) | (q11 << 24));
    };

    v4i d0, d1, d2, d3, d4, d5, d6, d7;
    auto ISSUE = [&](int slot) {
        const uint4* rp = reinterpret_cast<const uint4*>(&cobuf[w][slot][18 * g]);
        const uint4 N0 = rp[0], N1 = rp[1], N2 = rp[2], N3 = rp[3];
        d0 = llvm_amdgcn_raw_buffer_load_v4i32(srd.v, (int)((N0.x << 7) | qoff), 0, 0);
        d1 = llvm_amdgcn_raw_buffer_load_v4i32(srd.v, (int)((N0.z << 7) | qoff), 0, 0);
        d2 = llvm_amdgcn_raw_buffer_load_v4i32(srd.v, (int)((N1.x << 7) | qoff), 0, 0);
        d3 = llvm_amdgcn_raw_buffer_load_v4i32(srd.v, (int)((N1.z << 7) | qoff), 0, 0);
        d4 = llvm_amdgcn_raw_buffer_load_v4i32(srd.v, (int)((N2.x << 7) | qoff), 0, 0);
        d5 = llvm_amdgcn_raw_buffer_load_v4i32(srd.v, (int)((N2.z << 7) | qoff), 0, 0);
        d6 = llvm_amdgcn_raw_buffer_load_v4i32(srd.v, (int)((N3.x << 7) | qoff), 0, 0);
        d7 = llvm_amdgcn_raw_buffer_load_v4i32(srd.v, (int)((N3.z << 7) | qoff), 0, 0);
    };

    auto BODY = [&](int jl, int S, bool doIssue, bool doCoord) {
        const uint4* rp = reinterpret_cast<const uint4*>(&cobuf[w][S][18 * g]);
        const uint4 A = rp[0], B = rp[1], C4 = rp[2], D4 = rp[3];
        int r0 = 0, r1 = 0, r2 = 0, r3 = 0;
        #define TAP(dp, Wp, pp)                                         \
            r0 = dot4u((unsigned)dp.x, Wp, r0);                          \
            r1 = dot4u((unsigned)dp.y, Wp, r1);                          \
            r2 = dot4u((unsigned)dp.z, Wp, r2);                          \
            r3 = dot4u((unsigned)dp.w, Wp, r3);                          \
            colv[pp][0] = dot4u((unsigned)dp.x, Wp, colv[pp][0]);        \
            colv[pp][1] = dot4u((unsigned)dp.y, Wp, colv[pp][1]);        \
            colv[pp][2] = dot4u((unsigned)dp.z, Wp, colv[pp][2]);        \
            colv[pp][3] = dot4u((unsigned)dp.w, Wp, colv[pp][3]);
        TAP(d0, A.y,  0)
        TAP(d1, A.w,  1)
        TAP(d2, B.y,  2)
        TAP(d3, B.w,  3)
        TAP(d4, C4.y, 4)
        TAP(d5, C4.w, 5)
        TAP(d6, D4.y, 6)
        TAP(d7, D4.w, 7)
        #undef TAP
        if (doIssue) ISSUE(S ^ 1);
        if (doCoord) COORD(jl + 2, S);
        #pragma unroll
        for (int off = 32; off >= 8; off >>= 1) {
            r0 += __shfl_down(r0, off, 64);
            r1 += __shfl_down(r1, off, 64);
            r2 += __shfl_down(r2, off, 64);
            r3 += __shfl_down(r3, off, 64);
        }
        if (l < 8) {
            atomicAdd(&row_lds[jl * 33 + 4 * l + 0], r0);
            atomicAdd(&row_lds[jl * 33 + 4 * l + 1], r1);
            atomicAdd(&row_lds[jl * 33 + 4 * l + 2], r2);
            atomicAdd(&row_lds[jl * 33 + 4 * l + 3], r3);
        }
    };

    __syncthreads();   // row_lds zeroed before any wave's ds atomics

    COORD(0, 0);
    COORD(1, 1);
    ISSUE(0);
    for (int jo = 0; jo < 31; ++jo) {
        BODY(2 * jo,     0, true, true);
        BODY(2 * jo + 1, 1, true, true);
    }
    BODY(62, 0, true,  false);
    BODY(63, 1, false, false);

    // ---- columns: slab (a,jc); i-halves write disjoint i-ranges ----
    int* cp = colpart +
        ((size_t)(a * NCH + jc) * 512 + 256 * ih + 64 * w + 8 * g) * 32 + 4 * q;
    #pragma unroll
    for (int p = 0; p < 8; ++p) {
        *reinterpret_cast<int4*>(cp + p * 32) =
            make_int4(colv[p][0], colv[p][1], colv[p][2], colv[p][3]);
    }

    __syncthreads();

    // ---- rows: int partials per i-half, block-exclusive ----
    int* rp_ = rowpart + ((size_t)ih * NA2 + a) * 512 * 32;
    for (int e = t; e < 64 * 32; e += 256) {
        const int jl = e >> 5, n = e & 31;
        rp_[(size_t)(j0 + jl) * 32 + n] = row_lds[jl * 33 + n];
    }
}

// ---------------------------------------------------------------------------
// Round-9 kernel (169 us, proven): 8-wave blocks, 2-deep pipeline, (512,2).
// Kept as second tier.
// ---------------------------------------------------------------------------
__global__ __launch_bounds__(512, 2) void radon_sym8(
    const uint4* __restrict__ xq, float* __restrict__ ws2,
    int* __restrict__ colpart) {
    const int gid = blockIdx.x;       // 90*8 = 720
    const int a   = gid >> 3;
    const int ch  = gid & 7;
    const int j0  = ch << 6;

    const int t = threadIdx.x;
    const int w = t >> 6;
    const int l = t & 63;
    const int g = l >> 3;
    const int q = l & 7;
    const int qoff = q << 4;

    __shared__ uint2 cobuf[8][4][144];
    __shared__ int   row_lds[64 * 33];

    for (int e = t; e < 64 * 33; e += 512) row_lds[e] = 0;

    union { v4i v; struct { unsigned lo, hi, sz, cfg; } s; } srd;
    srd.s.lo  = (unsigned)(size_t)xq;
    srd.s.hi  = (unsigned)((size_t)xq >> 32);
    srd.s.sz  = (unsigned)NR2 * 128u;
    srd.s.cfg = 0x00020000u;

    const float theta = (float)a * (float)(M_PI / 180.0);
    float s, c;
    sincosf(theta, &s, &c);
    const float fi = (float)(64 * w + l);

    int colv[8][4];
    #pragma unroll
    for (int p = 0; p < 8; ++p)
        #pragma unroll
        for (int m = 0; m < 4; ++m) colv[p][m] = 0;

    auto COORD = [&](int jl, int slot) {
        const int j = j0 + jl;
        const float cj = ((float)j + 0.5f) * (2.0f / 512.0f) - 1.0f;
        const float P = 256.0f * c * cj + s * (0.5f - 256.0f) + 255.5f;
        const float Q = -256.0f * s * cj + c * (0.5f - 256.0f) + 255.5f;
        const float ix = fminf(fmaxf(fmaf(fi, s, P), -1.0f), 511.9995f);
        const float iy = fminf(fmaxf(fmaf(fi, c, Q), -1.0f), 511.9995f);
        const float ix0f = floorf(ix), iy0f = floorf(iy);
        const float wx1 = ix - ix0f, wy1 = iy - iy0f;
        const float wx0 = 1.0f - wx1, wy0 = 1.0f - wy1;
        const unsigned q00 = (unsigned)fmaf(wy0 * wx0, 127.0f, 0.5f);
        const unsigned q01 = (unsigned)fmaf(wy0 * wx1, 127.0f, 0.5f);
        const unsigned q10 = (unsigned)fmaf(wy1 * wx0, 127.0f, 0.5f);
        const unsigned q11 = (unsigned)fmaf(wy1 * wx1, 127.0f, 0.5f);
        cobuf[w][slot][18 * g + q] =
            make_uint2((unsigned)(((int)iy0f + 1) * PW2 + ((int)ix0f + 1)),
                       q00 | (q01 << 8) | (q10 << 16) | (q11 << 24));
    };

    v4i dA0, dA1, dA2, dA3, dA4, dA5, dA6, dA7;
    v4i dB0, dB1, dB2, dB3, dB4, dB5, dB6, dB7;

    auto ISSUE_A = [&](int slot) {
        const uint4* rp = reinterpret_cast<const uint4*>(&cobuf[w][slot][18 * g]);
        const uint4 N0 = rp[0], N1 = rp[1], N2 = rp[2], N3 = rp[3];
        dA0 = llvm_amdgcn_raw_buffer_load_v4i32(srd.v, (int)((N0.x << 7) | qoff), 0, 0);
        dA1 = llvm_amdgcn_raw_buffer_load_v4i32(srd.v, (int)((N0.z << 7) | qoff), 0, 0);
        dA2 = llvm_amdgcn_raw_buffer_load_v4i32(srd.v, (int)((N1.x << 7) | qoff), 0, 0);
        dA3 = llvm_amdgcn_raw_buffer_load_v4i32(srd.v, (int)((N1.z << 7) | qoff), 0, 0);
        dA4 = llvm_amdgcn_raw_buffer_load_v4i32(srd.v, (int)((N2.x << 7) | qoff), 0, 0);
        dA5 = llvm_amdgcn_raw_buffer_load_v4i32(srd.v, (int)((N2.z << 7) | qoff), 0, 0);
        dA6 = llvm_amdgcn_raw_buffer_load_v4i32(srd.v, (int)((N3.x << 7) | qoff), 0, 0);
        dA7 = llvm_amdgcn_raw_buffer_load_v4i32(srd.v, (int)((N3.z << 7) | qoff), 0, 0);
    };
    auto ISSUE_B = [&](int slot) {
        const uint4* rp = reinterpret_cast<const uint4*>(&cobuf[w][slot][18 * g]);
        const uint4 N0 = rp[0], N1 = rp[1], N2 = rp[2], N3 = rp[3];
        dB0 = llvm_amdgcn_raw_buffer_load_v4i32(srd.v, (int)((N0.x << 7) | qoff), 0, 0);
        dB1 = llvm_amdgcn_raw_buffer_load_v4i32(srd.v, (int)((N0.z << 7) | qoff), 0, 0);
        dB2 = llvm_amdgcn_raw_buffer_load_v4i32(srd.v, (int)((N1.x << 7) | qoff), 0, 0);
        dB3 = llvm_amdgcn_raw_buffer_load_v4i32(srd.v, (int)((N1.z << 7) | qoff), 0, 0);
        dB4 = llvm_amdgcn_raw_buffer_load_v4i32(srd.v, (int)((N2.x << 7) | qoff), 0, 0);
        dB5 = llvm_amdgcn_raw_buffer_load_v4i32(srd.v, (int)((N2.z << 7) | qoff), 0, 0);
        dB6 = llvm_amdgcn_raw_buffer_load_v4i32(srd.v, (int)((N3.x << 7) | qoff), 0, 0);
        dB7 = llvm_amdgcn_raw_buffer_load_v4i32(srd.v, (int)((N3.z << 7) | qoff), 0, 0);
    };

    #define TAPX(dp, Wp, pp)                                        \
        r0 = dot4u((unsigned)dp.x, Wp, r0);                          \
        r1 = dot4u((unsigned)dp.y, Wp, r1);                          \
        r2 = dot4u((unsigned)dp.z, Wp, r2);                          \
        r3 = dot4u((unsigned)dp.w, Wp, r3);                          \
        colv[pp][0] = dot4u((unsigned)dp.x, Wp, colv[pp][0]);        \
        colv[pp][1] = dot4u((unsigned)dp.y, Wp, colv[pp][1]);        \
        colv[pp][2] = dot4u((unsigned)dp.z, Wp, colv[pp][2]);        \
        colv[pp][3] = dot4u((unsigned)dp.w, Wp, colv[pp][3]);

    #define REDUCE_STORE(jl)                                        \
        _Pragma("unroll")                                            \
        for (int off = 32; off >= 8; off >>= 1) {                    \
            r0 += __shfl_down(r0, off, 64);                          \
            r1 += __shfl_down(r1, off, 64);                          \
            r2 += __shfl_down(r2, off, 64);                          \
            r3 += __shfl_down(r3, off, 64);                          \
        }                                                            \
        if (l < 8) {                                                 \
            atomicAdd(&row_lds[(jl) * 33 + 4 * l + 0], r0);          \
            atomicAdd(&row_lds[(jl) * 33 + 4 * l + 1], r1);          \
            atomicAdd(&row_lds[(jl) * 33 + 4 * l + 2], r2);          \
            atomicAdd(&row_lds[(jl) * 33 + 4 * l + 3], r3);          \
        }

    auto BODY_A = [&](int jl, bool doIssue, bool doCoord) {
        const int S = jl & 3;
        const uint4* rp = reinterpret_cast<const uint4*>(&cobuf[w][S][18 * g]);
        const uint4 A = rp[0], B = rp[1], C4 = rp[2], D4 = rp[3];
        int r0 = 0, r1 = 0, r2 = 0, r3 = 0;
        TAPX(dA0, A.y,  0) TAPX(dA1, A.w,  1)
        TAPX(dA2, B.y,  2) TAPX(dA3, B.w,  3)
        TAPX(dA4, C4.y, 4) TAPX(dA5, C4.w, 5)
        TAPX(dA6, D4.y, 6) TAPX(dA7, D4.w, 7)
        if (doIssue) ISSUE_A((jl + 2) & 3);
        if (doCoord) COORD(jl + 4, S);
        REDUCE_STORE(jl)
    };
    auto BODY_B = [&](int jl, bool doIssue, bool doCoord) {
        const int S = jl & 3;
        const uint4* rp = reinterpret_cast<const uint4*>(&cobuf[w][S][18 * g]);
        const uint4 A = rp[0], B = rp[1], C4 = rp[2], D4 = rp[3];
        int r0 = 0, r1 = 0, r2 = 0, r3 = 0;
        TAPX(dB0, A.y,  0) TAPX(dB1, A.w,  1)
        TAPX(dB2, B.y,  2) TAPX(dB3, B.w,  3)
        TAPX(dB4, C4.y, 4) TAPX(dB5, C4.w, 5)
        TAPX(dB6, D4.y, 6) TAPX(dB7, D4.w, 7)
        if (doIssue) ISSUE_B((jl + 2) & 3);
        if (doCoord) COORD(jl + 4, S);
        REDUCE_STORE(jl)
    };

    __syncthreads();

    COORD(0, 0); COORD(1, 1); COORD(2, 2); COORD(3, 3);
    ISSUE_A(0);
    ISSUE_B(1);
    for (int jo = 0; jo < 30; ++jo) {
        BODY_A(2 * jo,     true, true);
        BODY_B(2 * jo + 1, true, true);
    }
    BODY_A(60, true,  false);
    BODY_B(61, true,  false);
    BODY_A(62, false, false);
    BODY_B(63, false, false);

    #undef TAPX
    #undef REDUCE_STORE

    int* cp = colpart + ((size_t)gid * 512 + 64 * w + 8 * g) * 32 + 4 * q;
    #pragma unroll
    for (int p = 0; p < 8; ++p) {
        *reinterpret_cast<int4*>(cp + p * 32) =
            make_int4(colv[p][0], colv[p][1], colv[p][2], colv[p][3]);
    }

    __syncthreads();

    const float k1 = 1.0f / 16129.0f;
    for (int e = t; e < 64 * 32; e += 512) {
        const int jl = e >> 5, n = e & 31;
        ws2[((size_t)a * 512 + (j0 + jl)) * 32 + n] = (float)row_lds[jl * 33 + n] * k1;
    }
}

// ---------------------------------------------------------------------------
// Fallback main kernel (no symmetry): one wave per line, all 180 angles.
// ---------------------------------------------------------------------------
template <bool STAGED>
__global__ __launch_bounds__(256) void radon_q8c(
    const uint4* __restrict__ xq, float* __restrict__ dst) {
    const int gid = blockIdx.x;
    const int jb8 = gid & 7;
    const int r_  = gid >> 3;
    const int jr4 = r_ & 7;
    const int r2  = r_ >> 3;
    const int a   = r2 % NA;
    const int sl  = r2 / NA;

    const int t = threadIdx.x;
    const int w = t >> 6;
    const int l = t & 63;
    const int q = l & 7;
    const int g = l >> 3;
    const int qoff = q << 4;
    const int j = (((sl << 3) | jb8) << 5) | (jr4 << 2) | w;

    union { v4i v; struct { unsigned lo, hi, sz, cfg; } s; } srd;
    srd.s.lo  = (unsigned)(size_t)xq;
    srd.s.hi  = (unsigned)((size_t)xq >> 32);
    srd.s.sz  = (unsigned)NR2 * 128u;
    srd.s.cfg = 0x00020000u;

    const float theta = (float)a * (float)(M_PI / 180.0);
    float s, c;
    sincosf(theta, &s, &c);
    const float cj = ((float)j + 0.5f) * (2.0f / 512.0f) - 1.0f;
    const float P = 256.0f * c * cj + s * (0.5f - 256.0f) + 255.5f;
    const float Q = -256.0f * s * cj + c * (0.5f - 256.0f) + 255.5f;

    __shared__ uint2 lds_rw[4][528];

    uint2 rw[8];
    #pragma unroll
    for (int m = 0; m < 8; ++m) {
        const float fi = (float)(8 * l + m);
        const float ix = fminf(fmaxf(fmaf(fi, s, P), -1.0f), 511.9995f);
        const float iy = fminf(fmaxf(fmaf(fi, c, Q), -1.0f), 511.9995f);
        const float ix0f = floorf(ix), iy0f = floorf(iy);
        const float wx1 = ix - ix0f, wy1 = iy - iy0f;
        const float wx0 = 1.0f - wx1, wy0 = 1.0f - wy1;
        const unsigned q00 = (unsigned)fmaf(wy0 * wx0, 127.0f, 0.5f);
        const unsigned q01 = (unsigned)fmaf(wy0 * wx1, 127.0f, 0.5f);
        const unsigned q10 = (unsigned)fmaf(wy1 * wx0, 127.0f, 0.5f);
        const unsigned q11 = (unsigned)fmaf(wy1 * wx1, 127.0f, 0.5f);
        rw[m].x = (unsigned)(((int)iy0f + 1) * PW2 + ((int)ix0f + 1));
        rw[m].y = q00 | (q01 << 8) | (q10 << 16) | (q11 << 24);
    }
    {
        uint4* wp = reinterpret_cast<uint4*>(&lds_rw[w][8 * l + 2 * g]);
        wp[0] = make_uint4(rw[0].x, rw[0].y, rw[1].x, rw[1].y);
        wp[1] = make_uint4(rw[2].x, rw[2].y, rw[3].x, rw[3].y);
        wp[2] = make_uint4(rw[4].x, rw[4].y, rw[5].x, rw[5].y);
        wp[3] = make_uint4(rw[6].x, rw[6].y, rw[7].x, rw[7].y);
    }

    int acc0 = 0, acc1 = 0, acc2 = 0, acc3 = 0;
    const uint2* rb = &lds_rw[w][66 * g];

    #pragma unroll
    for (int ch = 0; ch < 8; ++ch) {
        const uint4* rp = reinterpret_cast<const uint4*>(rb + 8 * ch);
        const uint4 A  = rp[0];
        const uint4 B  = rp[1];
        const uint4 C4 = rp[2];
        const uint4 D4 = rp[3];

        v4i d0 = llvm_amdgcn_raw_buffer_load_v4i32(srd.v, (int)((A.x  << 7) | qoff), 0, 0);
        v4i d1 = llvm_amdgcn_raw_buffer_load_v4i32(srd.v, (int)((A.z  << 7) | qoff), 0, 0);
        v4i d2 = llvm_amdgcn_raw_buffer_load_v4i32(srd.v, (int)((B.x  << 7) | qoff), 0, 0);
        v4i d3 = llvm_amdgcn_raw_buffer_load_v4i32(srd.v, (int)((B.z  << 7) | qoff), 0, 0);
        v4i d4 = llvm_amdgcn_raw_buffer_load_v4i32(srd.v, (int)((C4.x << 7) | qoff), 0, 0);
        v4i d5 = llvm_amdgcn_raw_buffer_load_v4i32(srd.v, (int)((C4.z << 7) | qoff), 0, 0);
        v4i d6 = llvm_amdgcn_raw_buffer_load_v4i32(srd.v, (int)((D4.x << 7) | qoff), 0, 0);
        v4i d7 = llvm_amdgcn_raw_buffer_load_v4i32(srd.v, (int)((D4.z << 7) | qoff), 0, 0);

        #define TAPF(dp, Wp)                              \
            acc0 = dot4u((unsigned)dp.x, Wp, acc0);        \
            acc1 = dot4u((unsigned)dp.y, Wp, acc1);        \
            acc2 = dot4u((unsigned)dp.z, Wp, acc2);        \
            acc3 = dot4u((unsigned)dp.w, Wp, acc3);
        TAPF(d0, A.y)
        TAPF(d1, A.w)
        TAPF(d2, B.y)
        TAPF(d3, B.w)
        TAPF(d4, C4.y)
        TAPF(d5, C4.w)
        TAPF(d6, D4.y)
        TAPF(d7, D4.w)
        #undef TAPF
    }

    #pragma unroll
    for (int off = 32; off >= 8; off >>= 1) {
        acc0 += __shfl_down(acc0, off, 64);
        acc1 += __shfl_down(acc1, off, 64);
        acc2 += __shfl_down(acc2, off, 64);
        acc3 += __shfl_down(acc3, off, 64);
    }

    if (l < 8) {
        const float k1 = 1.0f / 16129.0f;
        if (STAGED) {
            float4 v = make_float4((float)acc0 * k1, (float)acc1 * k1,
                                   (float)acc2 * k1, (float)acc3 * k1);
            *reinterpret_cast<float4*>(dst + (((size_t)a * 512 + j) << 5) + 4 * l) = v;
        } else {
            const int n0 = 4 * l;
            dst[((size_t)(n0 + 0) * 512 + j) * 180 + a] = (float)acc0 * k1;
            dst[((size_t)(n0 + 1) * 512 + j) * 180 + a] = (float)acc1 * k1;
            dst[((size_t)(n0 + 2) * 512 + j) * 180 + a] = (float)acc2 * k1;
            dst[((size_t)(n0 + 3) * 512 + j) * 180 + a] = (float)acc3 * k1;
        }
    }
}

// ---------------------------------------------------------------------------
// Merge + transpose for the v9 symmetric path:
// out[n][j][a]: a<90 -> sum of 2 int rowpart halves; a>=90 -> sum of 8
// colpart chunk slabs at [511-j].
// ---------------------------------------------------------------------------
__global__ __launch_bounds__(256) void sino_transpose_sym9(
    const int* __restrict__ rowpart, const int* __restrict__ colpart,
    float* __restrict__ out) {
    __shared__ float buf[NA * 33];
    const int j = blockIdx.x;
    const int t = threadIdx.x;
    const float k1 = 1.0f / 16129.0f;
    for (int e = t; e < NA * 32; e += 256) {
        const int aa = e >> 5, n = e & 31;
        float v;
        if (aa < NA2) {
            const size_t o = ((size_t)aa * 512 + j) * 32 + n;
            const size_t h = (size_t)NA2 * 512 * 32;
            v = (float)(rowpart[o] + rowpart[o + h]) * k1;
        } else {
            const size_t base = (((size_t)(aa - NA2) * NCH) * 512 + (511 - j)) * 32 + n;
            int sum = 0;
            #pragma unroll
            for (int ch = 0; ch < NCH; ++ch)
                sum += colpart[base + (size_t)ch * 512 * 32];
            v = (float)sum * k1;
        }
        buf[aa * 33 + n] = v;
    }
    __syncthreads();
    for (int e = t; e < NA * 32; e += 256) {
        const int n = e / NA, aa = e - n * NA;
        out[((size_t)n * 512 + j) * NA + aa] = buf[aa * 33 + n];
    }
}

// ---------------------------------------------------------------------------
// Merge + transpose for the sym8 fallback path (float ws2 rows).
// ---------------------------------------------------------------------------
__global__ __launch_bounds__(256) void sino_transpose_sym(
    const float* __restrict__ ws2, const int* __restrict__ colpart,
    float* __restrict__ out) {
    __shared__ float buf[NA * 33];
    const int j = blockIdx.x;
    const int t = threadIdx.x;
    const float k1 = 1.0f / 16129.0f;
    for (int e = t; e < NA * 32; e += 256) {
        const int aa = e >> 5, n = e & 31;
        float v;
        if (aa < NA2) {
            v = ws2[((size_t)aa * 512 + j) * 32 + n];
        } else {
            const size_t base = (((size_t)(aa - NA2) * NCH) * 512 + (511 - j)) * 32 + n;
            int sum = 0;
            #pragma unroll
            for (int ch = 0; ch < NCH; ++ch)
                sum += colpart[base + (size_t)ch * 512 * 32];
            v = (float)sum * k1;
        }
        buf[aa * 33 + n] = v;
    }
    __syncthreads();
    for (int e = t; e < NA * 32; e += 256) {
        const int n = e / NA, aa = e - n * NA;
        out[((size_t)n * 512 + j) * NA + aa] = buf[aa * 33 + n];
    }
}

// ---------------------------------------------------------------------------
// Plain transpose (fallback staged path).
// ---------------------------------------------------------------------------
__global__ __launch_bounds__(256) void sino_transpose(
    const float* __restrict__ ws2, float* __restrict__ out) {
    __shared__ float buf[NA * 33];
    const int j = blockIdx.x;
    const int t = threadIdx.x;
    for (int e = t; e < NA * 32; e += 256) {
        const int aa = e >> 5, n = e & 31;
        buf[aa * 33 + n] = ws2[((size_t)aa * 512 + j) * 32 + n];
    }
    __syncthreads();
    for (int e = t; e < NA * 32; e += 256) {
        const int n = e / NA, aa = e - n * NA;
        out[((size_t)n * 512 + j) * NA + aa] = buf[aa * 33 + n];
    }
}

// ---------------------------------------------------------------------------
// Fallback (ws too small): gather directly from x[n][y][x], fp32.
// ---------------------------------------------------------------------------
__global__ __launch_bounds__(256) void radon_direct(
    const float* __restrict__ x, float* __restrict__ out) {
    const int j = blockIdx.x;
    const int a = blockIdx.y;
    const int t = threadIdx.x;
    const int n = t & 31;
    const int ig = t >> 5;

    const float theta = (float)a * (float)(M_PI / 180.0);
    float s, c;
    sincosf(theta, &s, &c);
    const float cj = ((float)j + 0.5f) * (2.0f / 512.0f) - 1.0f;
    const float* __restrict__ img = x + (size_t)n * (IMG * IMG);

    float acc = 0.f;
    for (int k = 0; k < 64; ++k) {
        const int i = ig + 8 * k;
        const float ci = ((float)i + 0.5f) * (2.0f / 512.0f) - 1.0f;
        const float gx =  c * cj + s * ci;
        const float gy = -s * cj + c * ci;
        const float ix = ((gx + 1.0f) * 512.0f - 1.0f) * 0.5f;
        const float iy = ((gy + 1.0f) * 512.0f - 1.0f) * 0.5f;
        const float ix0f = floorf(ix), iy0f = floorf(iy);
        const float wx1 = ix - ix0f, wy1 = iy - iy0f;
        const float wx0 = 1.0f - wx1, wy0 = 1.0f - wy1;
        const float mx0 = (ix0f >=  0.0f && ix0f <= 511.0f) ? wx0 : 0.0f;
        const float mx1 = (ix0f >= -1.0f && ix0f <= 510.0f) ? wx1 : 0.0f;
        const float my0 = (iy0f >=  0.0f && iy0f <= 511.0f) ? wy0 : 0.0f;
        const float my1 = (iy0f >= -1.0f && iy0f <= 510.0f) ? wy1 : 0.0f;
        const int ix0 = (int)ix0f, iy0 = (int)iy0f;
        const int x0 = min(max(ix0, 0), 511);
        const int x1 = min(max(ix0 + 1, 0), 511);
        const int y0 = min(max(iy0, 0), 511);
        const int y1 = min(max(iy0 + 1, 0), 511);
        acc = fmaf(my0 * mx0, img[y0 * 512 + x0], acc);
        acc = fmaf(my0 * mx1, img[y0 * 512 + x1], acc);
        acc = fmaf(my1 * mx0, img[y1 * 512 + x0], acc);
        acc = fmaf(my1 * mx1, img[y1 * 512 + x1], acc);
    }

    acc += __shfl_down(acc, 32, 64);
    __shared__ float red[4][32];
    const int wave = t >> 6;
    if ((t & 63) < 32) red[wave][t & 31] = acc;
    __syncthreads();
    if (t < 32) {
        const float v = red[0][t] + red[1][t] + red[2][t] + red[3][t];
        out[((size_t)t * 512 + j) * 180 + a] = v;
    }
}

extern "C" void kernel_launch(void* const* d_in, const int* in_sizes, int n_in,
                              void* d_out, int out_size, void* d_ws, size_t ws_size,
                              hipStream_t stream) {
    const float* x = (const float*)d_in[0];
    float* out = (float*)d_out;

    const size_t xq_bytes   = (size_t)NR2 * 128;                         // 32.12 MiB
    const size_t row9_bytes = (size_t)2 * NA2 * 512 * 32 * sizeof(int);  // 22.5 MiB
    const size_t ws2_bytes  = (size_t)NA * 512 * 32 * sizeof(float);     // 11.25 MiB
    const size_t col_bytes  = (size_t)NA2 * NCH * 512 * 32 * sizeof(int);// 45 MiB
    const int grid_build = (NR2 + 63) / 64;

    if (ws_size >= xq_bytes + row9_bytes + col_bytes) {
        // v9 symmetric path: 4-wave blocks, i-halves, int row partials.
        uint4* xq = (uint4*)d_ws;
        int* rowpart = (int*)((char*)d_ws + xq_bytes);
        int* colpart = (int*)((char*)d_ws + xq_bytes + row9_bytes);
        unsigned char* xu8 = (unsigned char*)colpart;  // dead before radon writes
        quantize8<<<(IMG * IMG) / 64, 256, 0, stream>>>(x, xu8);
        build_quads8<<<grid_build, 256, 0, stream>>>(xu8, xq);
        radon_sym9<<<NA2 * NCH * 2, 256, 0, stream>>>(xq, rowpart, colpart);
        sino_transpose_sym9<<<512, 256, 0, stream>>>(rowpart, colpart, out);
    } else if (ws_size >= xq_bytes + ws2_bytes + col_bytes) {
        // round-9 path (169 us main kernel, proven)
        uint4* xq = (uint4*)d_ws;
        unsigned char* xu8 = (unsigned char*)d_ws + xq_bytes;
        float* ws2 = (float*)((char*)d_ws + xq_bytes);
        int* colpart = (int*)((char*)d_ws + xq_bytes + ws2_bytes);
        quantize8<<<(IMG * IMG) / 64, 256, 0, stream>>>(x, xu8);
        build_quads8<<<grid_build, 256, 0, stream>>>(xu8, xq);
        radon_sym8<<<NA2 * NCH, 512, 0, stream>>>(xq, ws2, colpart);
        sino_transpose_sym<<<512, 256, 0, stream>>>(ws2, colpart, out);
    } else if (ws_size >= xq_bytes + ws2_bytes) {
        uint4* xq = (uint4*)d_ws;
        unsigned char* xu8 = (unsigned char*)d_ws + xq_bytes;
        float* ws2 = (float*)((char*)d_ws + xq_bytes);
        quantize8<<<(IMG * IMG) / 64, 256, 0, stream>>>(x, xu8);
        build_quads8<<<grid_build, 256, 0, stream>>>(xu8, xq);
        radon_q8c<true><<<2 * NA * 8 * 8, 256, 0, stream>>>(xq, ws2);
        sino_transpose<<<512, 256, 0, stream>>>(ws2, out);
    } else if (ws_size >= xq_bytes) {
        uint4* xq = (uint4*)d_ws;
        build_quads<<<grid_build, 256, 0, stream>>>(x, xq);
        radon_q8c<false><<<2 * NA * 8 * 8, 256, 0, stream>>>(xq, out);
    } else {
        dim3 grid(IMG, NA);
        radon_direct<<<grid, 256, 0, stream>>>(x, out);
    }
}

// Round 11
// 233.698 us; speedup vs baseline: 4.5181x; 4.5181x over previous
//
#include <hip/hip_runtime.h>
#include <math.h>

#define IMG 512
#define NB 32
#define NA 180
#define NA2 90                   // angles actually gathered (90-deg symmetry)
#define PW2 513                  // padded cols: x in [-1, 511]
#define PH2 513                  // padded rows: y in [-1, 511]
#define NR2 (PW2 * PH2)          // 263169 records, 128 B each
#define NCH 8                    // 64-line chunks per angle

typedef int v4i __attribute__((ext_vector_type(4)));

// CK-style raw buffer load intrinsic mapping (32-bit voffset addressing).
__device__ v4i llvm_amdgcn_raw_buffer_load_v4i32(
    v4i srsrc, int voffset, int soffset, int aux) __asm("llvm.amdgcn.raw.buffer.load.v4i32");

// ---------------------------------------------------------------------------
// u8 dot4: acc += sum of byte-wise products (bytes <= 127: signed==unsigned).
// ---------------------------------------------------------------------------
__device__ __forceinline__ int dot4u(unsigned a, unsigned b, int c) {
#if __has_builtin(__builtin_amdgcn_udot4)
    return (int)__builtin_amdgcn_udot4(a, b, (unsigned)c, false);
#elif __has_builtin(__builtin_amdgcn_sdot4)
    return __builtin_amdgcn_sdot4((int)a, (int)b, c, false);
#else
    int s = c;
    s += (int)((a      ) & 0xffu) * (int)((b      ) & 0xffu);
    s += (int)((a >>  8) & 0xffu) * (int)((b >>  8) & 0xffu);
    s += (int)((a >> 16) & 0xffu) * (int)((b >> 16) & 0xffu);
    s += (int)((a >> 24)        ) * (int)((b >> 24)        );
    return s;
#endif
}

// ---------------------------------------------------------------------------
// Stage 1: quantize + transpose. x[n][y][x] fp32 -> xu8[y*512+x][n] u8.
// ---------------------------------------------------------------------------
__global__ __launch_bounds__(256) void quantize8(
    const float* __restrict__ x, unsigned char* __restrict__ xu8) {
    __shared__ float lds[64 * 33];
    const int p0  = blockIdx.x * 64;
    const int t   = threadIdx.x;
    const int pix = t & 63;
    const int nb  = t >> 6;  // 0..3

    #pragma unroll
    for (int k = 0; k < 8; ++k) {
        const int n = nb + 4 * k;
        lds[pix * 33 + n] = x[(size_t)n * (IMG * IMG) + p0 + pix];
    }
    __syncthreads();

    const int pp = t >> 2;
    const int n0 = (t & 3) * 8;
    unsigned w0 = 0, w1 = 0;
    #pragma unroll
    for (int m = 0; m < 4; ++m) {
        const unsigned b = (unsigned)fmaf(lds[pp * 33 + n0 + m], 127.0f, 0.5f);
        w0 |= b << (8 * m);
    }
    #pragma unroll
    for (int m = 0; m < 4; ++m) {
        const unsigned b = (unsigned)fmaf(lds[pp * 33 + n0 + 4 + m], 127.0f, 0.5f);
        w1 |= b << (8 * m);
    }
    uint2 st = make_uint2(w0, w1);
    *reinterpret_cast<uint2*>(xu8 + (size_t)(p0 + pp) * 32 + (t & 3) * 8) = st;
}

// ---------------------------------------------------------------------------
// Stage 2: build zero-padded u8 quad table from the u8 image.
// ---------------------------------------------------------------------------
__global__ __launch_bounds__(256) void build_quads8(
    const unsigned char* __restrict__ xu8, uint4* __restrict__ xq) {
    const int t = threadIdx.x;
    const int q = t & 3;
    const int r = blockIdx.x * 64 + (t >> 2);
    if (r >= NR2) return;
    const int row = r / PW2;
    const int col = r - row * PW2;
    const int y  = row - 1;
    const int xx = col - 1;

    const bool y0ok = (unsigned)y        < 512u;
    const bool y1ok = (unsigned)(y + 1)  < 512u;
    const bool x0ok = (unsigned)xx       < 512u;
    const bool x1ok = (unsigned)(xx + 1) < 512u;
    const int off = q * 8;

    const uint2 z = make_uint2(0u, 0u);
    uint2 a00 = z, a01 = z, a10 = z, a11 = z;
    if (y0ok && x0ok) a00 = *reinterpret_cast<const uint2*>(xu8 + (size_t)(y * IMG + xx) * 32 + off);
    if (y0ok && x1ok) a01 = *reinterpret_cast<const uint2*>(xu8 + (size_t)(y * IMG + xx + 1) * 32 + off);
    if (y1ok && x0ok) a10 = *reinterpret_cast<const uint2*>(xu8 + (size_t)((y + 1) * IMG + xx) * 32 + off);
    if (y1ok && x1ok) a11 = *reinterpret_cast<const uint2*>(xu8 + (size_t)((y + 1) * IMG + xx + 1) * 32 + off);

    unsigned w[8];
    #pragma unroll
    for (int m = 0; m < 4; ++m) {
        w[m] = ((a00.x >> (8 * m)) & 0xffu)
             | (((a01.x >> (8 * m)) & 0xffu) << 8)
             | (((a10.x >> (8 * m)) & 0xffu) << 16)
             | (((a11.x >> (8 * m)) & 0xffu) << 24);
        w[4 + m] = ((a00.y >> (8 * m)) & 0xffu)
                 | (((a01.y >> (8 * m)) & 0xffu) << 8)
                 | (((a10.y >> (8 * m)) & 0xffu) << 16)
                 | (((a11.y >> (8 * m)) & 0xffu) << 24);
    }
    xq[(size_t)r * 8 + q * 2]     = make_uint4(w[0], w[1], w[2], w[3]);
    xq[(size_t)r * 8 + q * 2 + 1] = make_uint4(w[4], w[5], w[6], w[7]);
}

// ---------------------------------------------------------------------------
// Legacy one-pass build (fallback path only).
// ---------------------------------------------------------------------------
__global__ __launch_bounds__(256) void build_quads(
    const float* __restrict__ x, uint4* __restrict__ xq) {
    const int t = threadIdx.x;
    const int q = t & 3;
    const int r = blockIdx.x * 64 + (t >> 2);
    if (r >= NR2) return;
    const int row = r / PW2;
    const int col = r - row * PW2;
    const int y  = row - 1;
    const int xx = col - 1;

    const bool y0ok = (unsigned)y        < 512u;
    const bool y1ok = (unsigned)(y + 1)  < 512u;
    const bool x0ok = (unsigned)xx       < 512u;
    const bool x1ok = (unsigned)(xx + 1) < 512u;
    const int ys0 = y0ok ? y : 0,  ys1 = y1ok ? y + 1 : 0;
    const int xs0 = x0ok ? xx : 0, xs1 = x1ok ? xx + 1 : 0;

    const float* base = x + (size_t)(q * 8) * (IMG * IMG);
    unsigned wv[8];
    #pragma unroll
    for (int m = 0; m < 8; ++m) {
        const float* p = base + (size_t)m * (IMG * IMG);
        const float v00 = (y0ok && x0ok) ? p[ys0 * IMG + xs0] : 0.0f;
        const float v01 = (y0ok && x1ok) ? p[ys0 * IMG + xs1] : 0.0f;
        const float v10 = (y1ok && x0ok) ? p[ys1 * IMG + xs0] : 0.0f;
        const float v11 = (y1ok && x1ok) ? p[ys1 * IMG + xs1] : 0.0f;
        const unsigned q00 = (unsigned)fmaf(v00, 127.0f, 0.5f);
        const unsigned q01 = (unsigned)fmaf(v01, 127.0f, 0.5f);
        const unsigned q10 = (unsigned)fmaf(v10, 127.0f, 0.5f);
        const unsigned q11 = (unsigned)fmaf(v11, 127.0f, 0.5f);
        wv[m] = q00 | (q01 << 8) | (q10 << 16) | (q11 << 24);
    }
    xq[(size_t)r * 8 + q * 2]     = make_uint4(wv[0], wv[1], wv[2], wv[3]);
    xq[(size_t)r * 8 + q * 2 + 1] = make_uint4(wv[4], wv[5], wv[6], wv[7]);
}

// ---------------------------------------------------------------------------
// Symmetric radon v10 = round-10's structure at the CORRECT launch bounds.
// LAUNCH-BOUNDS LAW (fits all 4 empirical points, rounds 6-10):
//   hipcc VGPR cap = 512 / (2 * arg2), independent of block size
//   (wave64 counted as 2 wave32 slots).
//   (512,2)->128 [92/104 obs OK]  (512,4)->64 [spill]  (256,4)->64 [spill]
//   (256,5)->48 [spill]  ==> arg2 MUST be 2 for this ~92-reg family.
// This kernel: radon_sym9 structure (verified correct in round 10) with
// (256,2): cap 128, demand ~92, residency becomes resource-determined:
// VGPR 92 -> 5 waves/SIMD -> 5 blocks/CU (LDS 17.9KB allows 8). 1440 blocks
// over 1280 slots = 1.125 rounds (~94% util) vs round-6's 1.4 rounds (~70%).
// Block = (angle, 64-line chunk jc, i-half ih), 4 waves; wave w owns
// i-segment 256*ih + [64w, 64w+64). Rows: shfl reduce + LDS atomics ->
// int rowpart[ih] slab (merged in transpose). Columns: register colv[8][4]
// -> colpart[a][jc] slab, i-halves disjoint. No global atomics, no memset.
// ---------------------------------------------------------------------------
__global__ __launch_bounds__(256, 2) void radon_sym10(
    const uint4* __restrict__ xq, int* __restrict__ rowpart,
    int* __restrict__ colpart) {
    const int gid = blockIdx.x;       // 90*8*2 = 1440
    const int a   = gid >> 4;         // 0..89
    const int rem = gid & 15;
    const int jc  = rem >> 1;         // 0..7 : 64-line chunk
    const int ih  = rem & 1;          // i-half
    const int j0  = jc << 6;

    const int t = threadIdx.x;
    const int w = t >> 6;             // wave 0..3
    const int l = t & 63;
    const int g = l >> 3;             // sample group (8 samples)
    const int q = l & 7;              // record slice: batches 4q..4q+3
    const int qoff = q << 4;

    __shared__ uint2 cobuf[4][2][144];   // [wave][slot][18g+q], conflict-free b128
    __shared__ int   row_lds[64 * 33];

    for (int e = t; e < 64 * 33; e += 256) row_lds[e] = 0;

    union { v4i v; struct { unsigned lo, hi, sz, cfg; } s; } srd;
    srd.s.lo  = (unsigned)(size_t)xq;
    srd.s.hi  = (unsigned)((size_t)xq >> 32);
    srd.s.sz  = (unsigned)NR2 * 128u;
    srd.s.cfg = 0x00020000u;

    const float theta = (float)a * (float)(M_PI / 180.0);
    float s, c;
    sincosf(theta, &s, &c);
    const float fi = (float)(256 * ih + 64 * w + l);   // this lane's sample i

    int colv[8][4];
    #pragma unroll
    for (int p = 0; p < 8; ++p)
        #pragma unroll
        for (int m = 0; m < 4; ++m) colv[p][m] = 0;

    auto COORD = [&](int jl, int slot) {
        const int j = j0 + jl;
        const float cj = ((float)j + 0.5f) * (2.0f / 512.0f) - 1.0f;
        const float P = 256.0f * c * cj + s * (0.5f - 256.0f) + 255.5f;
        const float Q = -256.0f * s * cj + c * (0.5f - 256.0f) + 255.5f;
        const float ix = fminf(fmaxf(fmaf(fi, s, P), -1.0f), 511.9995f);
        const float iy = fminf(fmaxf(fmaf(fi, c, Q), -1.0f), 511.9995f);
        const float ix0f = floorf(ix), iy0f = floorf(iy);
        const float wx1 = ix - ix0f, wy1 = iy - iy0f;
        const float wx0 = 1.0f - wx1, wy0 = 1.0f - wy1;
        const unsigned q00 = (unsigned)fmaf(wy0 * wx0, 127.0f, 0.5f);
        const unsigned q01 = (unsigned)fmaf(wy0 * wx1, 127.0f, 0.5f);
        const unsigned q10 = (unsigned)fmaf(wy1 * wx0, 127.0f, 0.5f);
        const unsigned q11 = (unsigned)fmaf(wy1 * wx1, 127.0f, 0.5f);
        cobuf[w][slot][18 * g + q] =
            make_uint2((unsigned)(((int)iy0f + 1) * PW2 + ((int)ix0f + 1)),
                       q00 | (q01 << 8) | (q10 << 16) | (q11 << 24));
    };

    v4i d0, d1, d2, d3, d4, d5, d6, d7;
    auto ISSUE = [&](int slot) {
        const uint4* rp = reinterpret_cast<const uint4*>(&cobuf[w][slot][18 * g]);
        const uint4 N0 = rp[0], N1 = rp[1], N2 = rp[2], N3 = rp[3];
        d0 = llvm_amdgcn_raw_buffer_load_v4i32(srd.v, (int)((N0.x << 7) | qoff), 0, 0);
        d1 = llvm_amdgcn_raw_buffer_load_v4i32(srd.v, (int)((N0.z << 7) | qoff), 0, 0);
        d2 = llvm_amdgcn_raw_buffer_load_v4i32(srd.v, (int)((N1.x << 7) | qoff), 0, 0);
        d3 = llvm_amdgcn_raw_buffer_load_v4i32(srd.v, (int)((N1.z << 7) | qoff), 0, 0);
        d4 = llvm_amdgcn_raw_buffer_load_v4i32(srd.v, (int)((N2.x << 7) | qoff), 0, 0);
        d5 = llvm_amdgcn_raw_buffer_load_v4i32(srd.v, (int)((N2.z << 7) | qoff), 0, 0);
        d6 = llvm_amdgcn_raw_buffer_load_v4i32(srd.v, (int)((N3.x << 7) | qoff), 0, 0);
        d7 = llvm_amdgcn_raw_buffer_load_v4i32(srd.v, (int)((N3.z << 7) | qoff), 0, 0);
    };

    auto BODY = [&](int jl, int S, bool doIssue, bool doCoord) {
        const uint4* rp = reinterpret_cast<const uint4*>(&cobuf[w][S][18 * g]);
        const uint4 A = rp[0], B = rp[1], C4 = rp[2], D4 = rp[3];
        int r0 = 0, r1 = 0, r2 = 0, r3 = 0;
        #define TAP(dp, Wp, pp)                                         \
            r0 = dot4u((unsigned)dp.x, Wp, r0);                          \
            r1 = dot4u((unsigned)dp.y, Wp, r1);                          \
            r2 = dot4u((unsigned)dp.z, Wp, r2);                          \
            r3 = dot4u((unsigned)dp.w, Wp, r3);                          \
            colv[pp][0] = dot4u((unsigned)dp.x, Wp, colv[pp][0]);        \
            colv[pp][1] = dot4u((unsigned)dp.y, Wp, colv[pp][1]);        \
            colv[pp][2] = dot4u((unsigned)dp.z, Wp, colv[pp][2]);        \
            colv[pp][3] = dot4u((unsigned)dp.w, Wp, colv[pp][3]);
        TAP(d0, A.y,  0)
        TAP(d1, A.w,  1)
        TAP(d2, B.y,  2)
        TAP(d3, B.w,  3)
        TAP(d4, C4.y, 4)
        TAP(d5, C4.w, 5)
        TAP(d6, D4.y, 6)
        TAP(d7, D4.w, 7)
        #undef TAP
        if (doIssue) ISSUE(S ^ 1);
        if (doCoord) COORD(jl + 2, S);
        #pragma unroll
        for (int off = 32; off >= 8; off >>= 1) {
            r0 += __shfl_down(r0, off, 64);
            r1 += __shfl_down(r1, off, 64);
            r2 += __shfl_down(r2, off, 64);
            r3 += __shfl_down(r3, off, 64);
        }
        if (l < 8) {
            atomicAdd(&row_lds[jl * 33 + 4 * l + 0], r0);
            atomicAdd(&row_lds[jl * 33 + 4 * l + 1], r1);
            atomicAdd(&row_lds[jl * 33 + 4 * l + 2], r2);
            atomicAdd(&row_lds[jl * 33 + 4 * l + 3], r3);
        }
    };

    __syncthreads();   // row_lds zeroed before any wave's ds atomics

    COORD(0, 0);
    COORD(1, 1);
    ISSUE(0);
    for (int jo = 0; jo < 31; ++jo) {
        BODY(2 * jo,     0, true, true);
        BODY(2 * jo + 1, 1, true, true);
    }
    BODY(62, 0, true,  false);
    BODY(63, 1, false, false);

    // ---- columns: slab (a,jc); i-halves write disjoint i-ranges ----
    int* cp = colpart +
        ((size_t)(a * NCH + jc) * 512 + 256 * ih + 64 * w + 8 * g) * 32 + 4 * q;
    #pragma unroll
    for (int p = 0; p < 8; ++p) {
        *reinterpret_cast<int4*>(cp + p * 32) =
            make_int4(colv[p][0], colv[p][1], colv[p][2], colv[p][3]);
    }

    __syncthreads();

    // ---- rows: int partials per i-half, block-exclusive ----
    int* rp_ = rowpart + ((size_t)ih * NA2 + a) * 512 * 32;
    for (int e = t; e < 64 * 32; e += 256) {
        const int jl = e >> 5, n = e & 31;
        rp_[(size_t)(j0 + jl) * 32 + n] = row_lds[jl * 33 + n];
    }
}

// ---------------------------------------------------------------------------
// Round-6 winner (161 us, proven): 8-wave blocks, single-deep, (512,2).
// Kept as second tier.
// ---------------------------------------------------------------------------
__global__ __launch_bounds__(512, 2) void radon_sym5(
    const uint4* __restrict__ xq, float* __restrict__ ws2,
    int* __restrict__ colpart) {
    const int gid = blockIdx.x;       // 90*8 = 720
    const int a   = gid >> 3;
    const int ch  = gid & 7;
    const int j0  = ch << 6;

    const int t = threadIdx.x;
    const int w = t >> 6;
    const int l = t & 63;
    const int g = l >> 3;
    const int q = l & 7;
    const int qoff = q << 4;

    __shared__ uint2 cobuf[8][2][144];
    __shared__ int   row_lds[64 * 33];

    for (int e = t; e < 64 * 33; e += 512) row_lds[e] = 0;

    union { v4i v; struct { unsigned lo, hi, sz, cfg; } s; } srd;
    srd.s.lo  = (unsigned)(size_t)xq;
    srd.s.hi  = (unsigned)((size_t)xq >> 32);
    srd.s.sz  = (unsigned)NR2 * 128u;
    srd.s.cfg = 0x00020000u;

    const float theta = (float)a * (float)(M_PI / 180.0);
    float s, c;
    sincosf(theta, &s, &c);
    const float fi = (float)(64 * w + l);

    int colv[8][4];
    #pragma unroll
    for (int p = 0; p < 8; ++p)
        #pragma unroll
        for (int m = 0; m < 4; ++m) colv[p][m] = 0;

    auto COORD = [&](int jl, int slot) {
        const int j = j0 + jl;
        const float cj = ((float)j + 0.5f) * (2.0f / 512.0f) - 1.0f;
        const float P = 256.0f * c * cj + s * (0.5f - 256.0f) + 255.5f;
        const float Q = -256.0f * s * cj + c * (0.5f - 256.0f) + 255.5f;
        const float ix = fminf(fmaxf(fmaf(fi, s, P), -1.0f), 511.9995f);
        const float iy = fminf(fmaxf(fmaf(fi, c, Q), -1.0f), 511.9995f);
        const float ix0f = floorf(ix), iy0f = floorf(iy);
        const float wx1 = ix - ix0f, wy1 = iy - iy0f;
        const float wx0 = 1.0f - wx1, wy0 = 1.0f - wy1;
        const unsigned q00 = (unsigned)fmaf(wy0 * wx0, 127.0f, 0.5f);
        const unsigned q01 = (unsigned)fmaf(wy0 * wx1, 127.0f, 0.5f);
        const unsigned q10 = (unsigned)fmaf(wy1 * wx0, 127.0f, 0.5f);
        const unsigned q11 = (unsigned)fmaf(wy1 * wx1, 127.0f, 0.5f);
        cobuf[w][slot][18 * g + q] =
            make_uint2((unsigned)(((int)iy0f + 1) * PW2 + ((int)ix0f + 1)),
                       q00 | (q01 << 8) | (q10 << 16) | (q11 << 24));
    };

    v4i d0, d1, d2, d3, d4, d5, d6, d7;
    auto ISSUE = [&](int slot) {
        const uint4* rp = reinterpret_cast<const uint4*>(&cobuf[w][slot][18 * g]);
        const uint4 N0 = rp[0], N1 = rp[1], N2 = rp[2], N3 = rp[3];
        d0 = llvm_amdgcn_raw_buffer_load_v4i32(srd.v, (int)((N0.x << 7) | qoff), 0, 0);
        d1 = llvm_amdgcn_raw_buffer_load_v4i32(srd.v, (int)((N0.z << 7) | qoff), 0, 0);
        d2 = llvm_amdgcn_raw_buffer_load_v4i32(srd.v, (int)((N1.x << 7) | qoff), 0, 0);
        d3 = llvm_amdgcn_raw_buffer_load_v4i32(srd.v, (int)((N1.z << 7) | qoff), 0, 0);
        d4 = llvm_amdgcn_raw_buffer_load_v4i32(srd.v, (int)((N2.x << 7) | qoff), 0, 0);
        d5 = llvm_amdgcn_raw_buffer_load_v4i32(srd.v, (int)((N2.z << 7) | qoff), 0, 0);
        d6 = llvm_amdgcn_raw_buffer_load_v4i32(srd.v, (int)((N3.x << 7) | qoff), 0, 0);
        d7 = llvm_amdgcn_raw_buffer_load_v4i32(srd.v, (int)((N3.z << 7) | qoff), 0, 0);
    };

    auto BODY = [&](int jl, int S, bool doIssue, bool doCoord) {
        const uint4* rp = reinterpret_cast<const uint4*>(&cobuf[w][S][18 * g]);
        const uint4 A = rp[0], B = rp[1], C4 = rp[2], D4 = rp[3];
        int r0 = 0, r1 = 0, r2 = 0, r3 = 0;
        #define TAP(dp, Wp, pp)                                         \
            r0 = dot4u((unsigned)dp.x, Wp, r0);                          \
            r1 = dot4u((unsigned)dp.y, Wp, r1);                          \
            r2 = dot4u((unsigned)dp.z, Wp, r2);                          \
            r3 = dot4u((unsigned)dp.w, Wp, r3);                          \
            colv[pp][0] = dot4u((unsigned)dp.x, Wp, colv[pp][0]);        \
            colv[pp][1] = dot4u((unsigned)dp.y, Wp, colv[pp][1]);        \
            colv[pp][2] = dot4u((unsigned)dp.z, Wp, colv[pp][2]);        \
            colv[pp][3] = dot4u((unsigned)dp.w, Wp, colv[pp][3]);
        TAP(d0, A.y,  0)
        TAP(d1, A.w,  1)
        TAP(d2, B.y,  2)
        TAP(d3, B.w,  3)
        TAP(d4, C4.y, 4)
        TAP(d5, C4.w, 5)
        TAP(d6, D4.y, 6)
        TAP(d7, D4.w, 7)
        #undef TAP
        if (doIssue) ISSUE(S ^ 1);
        if (doCoord) COORD(jl + 2, S);
        #pragma unroll
        for (int off = 32; off >= 8; off >>= 1) {
            r0 += __shfl_down(r0, off, 64);
            r1 += __shfl_down(r1, off, 64);
            r2 += __shfl_down(r2, off, 64);
            r3 += __shfl_down(r3, off, 64);
        }
        if (l < 8) {
            atomicAdd(&row_lds[jl * 33 + 4 * l + 0], r0);
            atomicAdd(&row_lds[jl * 33 + 4 * l + 1], r1);
            atomicAdd(&row_lds[jl * 33 + 4 * l + 2], r2);
            atomicAdd(&row_lds[jl * 33 + 4 * l + 3], r3);
        }
    };

    __syncthreads();

    COORD(0, 0);
    COORD(1, 1);
    ISSUE(0);
    for (int jo = 0; jo < 31; ++jo) {
        BODY(2 * jo,     0, true, true);
        BODY(2 * jo + 1, 1, true, true);
    }
    BODY(62, 0, true,  false);
    BODY(63, 1, false, false);

    int* cp = colpart + ((size_t)gid * 512 + 64 * w + 8 * g) * 32 + 4 * q;
    #pragma unroll
    for (int p = 0; p < 8; ++p) {
        *reinterpret_cast<int4*>(cp + p * 32) =
            make_int4(colv[p][0], colv[p][1], colv[p][2], colv[p][3]);
    }

    __syncthreads();

    const float k1 = 1.0f / 16129.0f;
    for (int e = t; e < 64 * 32; e += 512) {
        const int jl = e >> 5, n = e & 31;
        ws2[((size_t)a * 512 + (j0 + jl)) * 32 + n] = (float)row_lds[jl * 33 + n] * k1;
    }
}

// ---------------------------------------------------------------------------
// Fallback main kernel (no symmetry): one wave per line, all 180 angles.
// ---------------------------------------------------------------------------
template <bool STAGED>
__global__ __launch_bounds__(256) void radon_q8c(
    const uint4* __restrict__ xq, float* __restrict__ dst) {
    const int gid = blockIdx.x;
    const int jb8 = gid & 7;
    const int r_  = gid >> 3;
    const int jr4 = r_ & 7;
    const int r2  = r_ >> 3;
    const int a   = r2 % NA;
    const int sl  = r2 / NA;

    const int t = threadIdx.x;
    const int w = t >> 6;
    const int l = t & 63;
    const int q = l & 7;
    const int g = l >> 3;
    const int qoff = q << 4;
    const int j = (((sl << 3) | jb8) << 5) | (jr4 << 2) | w;

    union { v4i v; struct { unsigned lo, hi, sz, cfg; } s; } srd;
    srd.s.lo  = (unsigned)(size_t)xq;
    srd.s.hi  = (unsigned)((size_t)xq >> 32);
    srd.s.sz  = (unsigned)NR2 * 128u;
    srd.s.cfg = 0x00020000u;

    const float theta = (float)a * (float)(M_PI / 180.0);
    float s, c;
    sincosf(theta, &s, &c);
    const float cj = ((float)j + 0.5f) * (2.0f / 512.0f) - 1.0f;
    const float P = 256.0f * c * cj + s * (0.5f - 256.0f) + 255.5f;
    const float Q = -256.0f * s * cj + c * (0.5f - 256.0f) + 255.5f;

    __shared__ uint2 lds_rw[4][528];

    uint2 rw[8];
    #pragma unroll
    for (int m = 0; m < 8; ++m) {
        const float fi = (float)(8 * l + m);
        const float ix = fminf(fmaxf(fmaf(fi, s, P), -1.0f), 511.9995f);
        const float iy = fminf(fmaxf(fmaf(fi, c, Q), -1.0f), 511.9995f);
        const float ix0f = floorf(ix), iy0f = floorf(iy);
        const float wx1 = ix - ix0f, wy1 = iy - iy0f;
        const float wx0 = 1.0f - wx1, wy0 = 1.0f - wy1;
        const unsigned q00 = (unsigned)fmaf(wy0 * wx0, 127.0f, 0.5f);
        const unsigned q01 = (unsigned)fmaf(wy0 * wx1, 127.0f, 0.5f);
        const unsigned q10 = (unsigned)fmaf(wy1 * wx0, 127.0f, 0.5f);
        const unsigned q11 = (unsigned)fmaf(wy1 * wx1, 127.0f, 0.5f);
        rw[m].x = (unsigned)(((int)iy0f + 1) * PW2 + ((int)ix0f + 1));
        rw[m].y = q00 | (q01 << 8) | (q10 << 16) | (q11 << 24);
    }
    {
        uint4* wp = reinterpret_cast<uint4*>(&lds_rw[w][8 * l + 2 * g]);
        wp[0] = make_uint4(rw[0].x, rw[0].y, rw[1].x, rw[1].y);
        wp[1] = make_uint4(rw[2].x, rw[2].y, rw[3].x, rw[3].y);
        wp[2] = make_uint4(rw[4].x, rw[4].y, rw[5].x, rw[5].y);
        wp[3] = make_uint4(rw[6].x, rw[6].y, rw[7].x, rw[7].y);
    }

    int acc0 = 0, acc1 = 0, acc2 = 0, acc3 = 0;
    const uint2* rb = &lds_rw[w][66 * g];

    #pragma unroll
    for (int ch = 0; ch < 8; ++ch) {
        const uint4* rp = reinterpret_cast<const uint4*>(rb + 8 * ch);
        const uint4 A  = rp[0];
        const uint4 B  = rp[1];
        const uint4 C4 = rp[2];
        const uint4 D4 = rp[3];

        v4i d0 = llvm_amdgcn_raw_buffer_load_v4i32(srd.v, (int)((A.x  << 7) | qoff), 0, 0);
        v4i d1 = llvm_amdgcn_raw_buffer_load_v4i32(srd.v, (int)((A.z  << 7) | qoff), 0, 0);
        v4i d2 = llvm_amdgcn_raw_buffer_load_v4i32(srd.v, (int)((B.x  << 7) | qoff), 0, 0);
        v4i d3 = llvm_amdgcn_raw_buffer_load_v4i32(srd.v, (int)((B.z  << 7) | qoff), 0, 0);
        v4i d4 = llvm_amdgcn_raw_buffer_load_v4i32(srd.v, (int)((C4.x << 7) | qoff), 0, 0);
        v4i d5 = llvm_amdgcn_raw_buffer_load_v4i32(srd.v, (int)((C4.z << 7) | qoff), 0, 0);
        v4i d6 = llvm_amdgcn_raw_buffer_load_v4i32(srd.v, (int)((D4.x << 7) | qoff), 0, 0);
        v4i d7 = llvm_amdgcn_raw_buffer_load_v4i32(srd.v, (int)((D4.z << 7) | qoff), 0, 0);

        #define TAPF(dp, Wp)                              \
            acc0 = dot4u((unsigned)dp.x, Wp, acc0);        \
            acc1 = dot4u((unsigned)dp.y, Wp, acc1);        \
            acc2 = dot4u((unsigned)dp.z, Wp, acc2);        \
            acc3 = dot4u((unsigned)dp.w, Wp, acc3);
        TAPF(d0, A.y)
        TAPF(d1, A.w)
        TAPF(d2, B.y)
        TAPF(d3, B.w)
        TAPF(d4, C4.y)
        TAPF(d5, C4.w)
        TAPF(d6, D4.y)
        TAPF(d7, D4.w)
        #undef TAPF
    }

    #pragma unroll
    for (int off = 32; off >= 8; off >>= 1) {
        acc0 += __shfl_down(acc0, off, 64);
        acc1 += __shfl_down(acc1, off, 64);
        acc2 += __shfl_down(acc2, off, 64);
        acc3 += __shfl_down(acc3, off, 64);
    }

    if (l < 8) {
        const float k1 = 1.0f / 16129.0f;
        if (STAGED) {
            float4 v = make_float4((float)acc0 * k1, (float)acc1 * k1,
                                   (float)acc2 * k1, (float)acc3 * k1);
            *reinterpret_cast<float4*>(dst + (((size_t)a * 512 + j) << 5) + 4 * l) = v;
        } else {
            const int n0 = 4 * l;
            dst[((size_t)(n0 + 0) * 512 + j) * 180 + a] = (float)acc0 * k1;
            dst[((size_t)(n0 + 1) * 512 + j) * 180 + a] = (float)acc1 * k1;
            dst[((size_t)(n0 + 2) * 512 + j) * 180 + a] = (float)acc2 * k1;
            dst[((size_t)(n0 + 3) * 512 + j) * 180 + a] = (float)acc3 * k1;
        }
    }
}

// ---------------------------------------------------------------------------
// Merge + transpose for the v10 symmetric path:
// out[n][j][a]: a<90 -> sum of 2 int rowpart halves; a>=90 -> sum of 8
// colpart chunk slabs at [511-j].
// ---------------------------------------------------------------------------
__global__ __launch_bounds__(256) void sino_transpose_sym10(
    const int* __restrict__ rowpart, const int* __restrict__ colpart,
    float* __restrict__ out) {
    __shared__ float buf[NA * 33];
    const int j = blockIdx.x;
    const int t = threadIdx.x;
    const float k1 = 1.0f / 16129.0f;
    for (int e = t; e < NA * 32; e += 256) {
        const int aa = e >> 5, n = e & 31;
        float v;
        if (aa < NA2) {
            const size_t o = ((size_t)aa * 512 + j) * 32 + n;
            const size_t h = (size_t)NA2 * 512 * 32;
            v = (float)(rowpart[o] + rowpart[o + h]) * k1;
        } else {
            const size_t base = (((size_t)(aa - NA2) * NCH) * 512 + (511 - j)) * 32 + n;
            int sum = 0;
            #pragma unroll
            for (int ch = 0; ch < NCH; ++ch)
                sum += colpart[base + (size_t)ch * 512 * 32];
            v = (float)sum * k1;
        }
        buf[aa * 33 + n] = v;
    }
    __syncthreads();
    for (int e = t; e < NA * 32; e += 256) {
        const int n = e / NA, aa = e - n * NA;
        out[((size_t)n * 512 + j) * NA + aa] = buf[aa * 33 + n];
    }
}

// ---------------------------------------------------------------------------
// Merge + transpose for the sym5 fallback path (float ws2 rows).
// ---------------------------------------------------------------------------
__global__ __launch_bounds__(256) void sino_transpose_sym(
    const float* __restrict__ ws2, const int* __restrict__ colpart,
    float* __restrict__ out) {
    __shared__ float buf[NA * 33];
    const int j = blockIdx.x;
    const int t = threadIdx.x;
    const float k1 = 1.0f / 16129.0f;
    for (int e = t; e < NA * 32; e += 256) {
        const int aa = e >> 5, n = e & 31;
        float v;
        if (aa < NA2) {
            v = ws2[((size_t)aa * 512 + j) * 32 + n];
        } else {
            const size_t base = (((size_t)(aa - NA2) * NCH) * 512 + (511 - j)) * 32 + n;
            int sum = 0;
            #pragma unroll
            for (int ch = 0; ch < NCH; ++ch)
                sum += colpart[base + (size_t)ch * 512 * 32];
            v = (float)sum * k1;
        }
        buf[aa * 33 + n] = v;
    }
    __syncthreads();
    for (int e = t; e < NA * 32; e += 256) {
        const int n = e / NA, aa = e - n * NA;
        out[((size_t)n * 512 + j) * NA + aa] = buf[aa * 33 + n];
    }
}

// ---------------------------------------------------------------------------
// Plain transpose (fallback staged path).
// ---------------------------------------------------------------------------
__global__ __launch_bounds__(256) void sino_transpose(
    const float* __restrict__ ws2, float* __restrict__ out) {
    __shared__ float buf[NA * 33];
    const int j = blockIdx.x;
    const int t = threadIdx.x;
    for (int e = t; e < NA * 32; e += 256) {
        const int aa = e >> 5, n = e & 31;
        buf[aa * 33 + n] = ws2[((size_t)aa * 512 + j) * 32 + n];
    }
    __syncthreads();
    for (int e = t; e < NA * 32; e += 256) {
        const int n = e / NA, aa = e - n * NA;
        out[((size_t)n * 512 + j) * NA + aa] = buf[aa * 33 + n];
    }
}

// ---------------------------------------------------------------------------
// Fallback (ws too small): gather directly from x[n][y][x], fp32.
// ---------------------------------------------------------------------------
__global__ __launch_bounds__(256) void radon_direct(
    const float* __restrict__ x, float* __restrict__ out) {
    const int j = blockIdx.x;
    const int a = blockIdx.y;
    const int t = threadIdx.x;
    const int n = t & 31;
    const int ig = t >> 5;

    const float theta = (float)a * (float)(M_PI / 180.0);
    float s, c;
    sincosf(theta, &s, &c);
    const float cj = ((float)j + 0.5f) * (2.0f / 512.0f) - 1.0f;
    const float* __restrict__ img = x + (size_t)n * (IMG * IMG);

    float acc = 0.f;
    for (int k = 0; k < 64; ++k) {
        const int i = ig + 8 * k;
        const float ci = ((float)i + 0.5f) * (2.0f / 512.0f) - 1.0f;
        const float gx =  c * cj + s * ci;
        const float gy = -s * cj + c * ci;
        const float ix = ((gx + 1.0f) * 512.0f - 1.0f) * 0.5f;
        const float iy = ((gy + 1.0f) * 512.0f - 1.0f) * 0.5f;
        const float ix0f = floorf(ix), iy0f = floorf(iy);
        const float wx1 = ix - ix0f, wy1 = iy - iy0f;
        const float wx0 = 1.0f - wx1, wy0 = 1.0f - wy1;
        const float mx0 = (ix0f >=  0.0f && ix0f <= 511.0f) ? wx0 : 0.0f;
        const float mx1 = (ix0f >= -1.0f && ix0f <= 510.0f) ? wx1 : 0.0f;
        const float my0 = (iy0f >=  0.0f && iy0f <= 511.0f) ? wy0 : 0.0f;
        const float my1 = (iy0f >= -1.0f && iy0f <= 510.0f) ? wy1 : 0.0f;
        const int ix0 = (int)ix0f, iy0 = (int)iy0f;
        const int x0 = min(max(ix0, 0), 511);
        const int x1 = min(max(ix0 + 1, 0), 511);
        const int y0 = min(max(iy0, 0), 511);
        const int y1 = min(max(iy0 + 1, 0), 511);
        acc = fmaf(my0 * mx0, img[y0 * 512 + x0], acc);
        acc = fmaf(my0 * mx1, img[y0 * 512 + x1], acc);
        acc = fmaf(my1 * mx0, img[y1 * 512 + x0], acc);
        acc = fmaf(my1 * mx1, img[y1 * 512 + x1], acc);
    }

    acc += __shfl_down(acc, 32, 64);
    __shared__ float red[4][32];
    const int wave = t >> 6;
    if ((t & 63) < 32) red[wave][t & 31] = acc;
    __syncthreads();
    if (t < 32) {
        const float v = red[0][t] + red[1][t] + red[2][t] + red[3][t];
        out[((size_t)t * 512 + j) * 180 + a] = v;
    }
}

extern "C" void kernel_launch(void* const* d_in, const int* in_sizes, int n_in,
                              void* d_out, int out_size, void* d_ws, size_t ws_size,
                              hipStream_t stream) {
    const float* x = (const float*)d_in[0];
    float* out = (float*)d_out;

    const size_t xq_bytes   = (size_t)NR2 * 128;                         // 32.12 MiB
    const size_t row9_bytes = (size_t)2 * NA2 * 512 * 32 * sizeof(int);  // 22.5 MiB
    const size_t ws2_bytes  = (size_t)NA * 512 * 32 * sizeof(float);     // 11.25 MiB
    const size_t col_bytes  = (size_t)NA2 * NCH * 512 * 32 * sizeof(int);// 45 MiB
    const int grid_build = (NR2 + 63) / 64;

    if (ws_size >= xq_bytes + row9_bytes + col_bytes) {
        // v10 symmetric path: 4-wave blocks at (256,2) [cap 128, no spill].
        uint4* xq = (uint4*)d_ws;
        int* rowpart = (int*)((char*)d_ws + xq_bytes);
        int* colpart = (int*)((char*)d_ws + xq_bytes + row9_bytes);
        unsigned char* xu8 = (unsigned char*)colpart;  // dead before radon writes
        quantize8<<<(IMG * IMG) / 64, 256, 0, stream>>>(x, xu8);
        build_quads8<<<grid_build, 256, 0, stream>>>(xu8, xq);
        radon_sym10<<<NA2 * NCH * 2, 256, 0, stream>>>(xq, rowpart, colpart);
        sino_transpose_sym10<<<512, 256, 0, stream>>>(rowpart, colpart, out);
    } else if (ws_size >= xq_bytes + ws2_bytes + col_bytes) {
        // round-6 winner path (161 us main kernel)
        uint4* xq = (uint4*)d_ws;
        unsigned char* xu8 = (unsigned char*)d_ws + xq_bytes;
        float* ws2 = (float*)((char*)d_ws + xq_bytes);
        int* colpart = (int*)((char*)d_ws + xq_bytes + ws2_bytes);
        quantize8<<<(IMG * IMG) / 64, 256, 0, stream>>>(x, xu8);
        build_quads8<<<grid_build, 256, 0, stream>>>(xu8, xq);
        radon_sym5<<<NA2 * NCH, 512, 0, stream>>>(xq, ws2, colpart);
        sino_transpose_sym<<<512, 256, 0, stream>>>(ws2, colpart, out);
    } else if (ws_size >= xq_bytes + ws2_bytes) {
        uint4* xq = (uint4*)d_ws;
        unsigned char* xu8 = (unsigned char*)d_ws + xq_bytes;
        float* ws2 = (float*)((char*)d_ws + xq_bytes);
        quantize8<<<(IMG * IMG) / 64, 256, 0, stream>>>(x, xu8);
        build_quads8<<<grid_build, 256, 0, stream>>>(xu8, xq);
        radon_q8c<true><<<2 * NA * 8 * 8, 256, 0, stream>>>(xq, ws2);
        sino_transpose<<<512, 256, 0, stream>>>(ws2, out);
    } else if (ws_size >= xq_bytes) {
        uint4* xq = (uint4*)d_ws;
        build_quads<<<grid_build, 256, 0, stream>>>(x, xq);
        radon_q8c<false><<<2 * NA * 8 * 8, 256, 0, stream>>>(xq, out);
    } else {
        dim3 grid(IMG, NA);
        radon_direct<<<grid, 256, 0, stream>>>(x, out);
    }
}